// Round 8
// baseline (220.811 us; speedup 1.0000x reference)
//
#include <hip/hip_runtime.h>
#include <hip/hip_bf16.h>

typedef short bf16x8 __attribute__((ext_vector_type(8)));
typedef float f32x4 __attribute__((ext_vector_type(4)));

#define LDP 72  // flash P row stride

__device__ __forceinline__ float bf2f(ushort u) {
    union { unsigned int i; float f; } v; v.i = ((unsigned int)u) << 16; return v.f;
}
__device__ __forceinline__ ushort f2bf(float f) {
    union { float f; unsigned int i; } v; v.f = f;
    unsigned int x = v.i;
    x += 0x7fffu + ((x >> 16) & 1u);  // RNE (finite values only)
    return (ushort)(x >> 16);
}
// packed 2x f32->bf16 (v_cvt_pk_bf16_f32 on gfx950), RNE
__device__ __forceinline__ ushort2 pk2bf(float a, float b) {
    union { __hip_bfloat162 h2; ushort2 u2; } cv;
    cv.h2 = __float22bfloat162_rn(float2{a, b});
    return cv.u2;
}

#define MFMA(a, b, c) __builtin_amdgcn_mfma_f32_16x16x32_bf16(a, b, c, 0, 0, 0)

// async global->LDS, 16B/lane; LDS dest = wave-uniform base + lane*16
__device__ __forceinline__ void gld_lds16(const ushort* g, ushort* l) {
    __builtin_amdgcn_global_load_lds(
        (const __attribute__((address_space(1))) unsigned int*)g,
        (__attribute__((address_space(3))) unsigned int*)l, 16, 0, 0);
}

// ws layout (ushort elems)
#define WS_XT 0
#define WS_XS 4194304
#define WS_WQ 8388608
#define WS_WK 9437184
#define WS_WV 10485760
#define WS_WO 11534336
#define WS_QH 12582912
#define WS_KH 16777216
#define WS_VT 20971520
#define WS_AO 0   // reuses XT region (XT dead after qkv_gemm)

// ---------------- cast: fp32 -> bf16 into ws ----------------
__global__ __launch_bounds__(256) void cast_bf16(
    const float* __restrict__ s0, const float* __restrict__ s1,
    const float* __restrict__ s2, const float* __restrict__ s3,
    const float* __restrict__ s4, const float* __restrict__ s5,
    ushort* __restrict__ ws)
{
    const int seg = blockIdx.y;
    const float* src = seg == 0 ? s0 : seg == 1 ? s1 : seg == 2 ? s2
                     : seg == 3 ? s3 : seg == 4 ? s4 : s5;
    const size_t off = seg == 0 ? WS_XT : seg == 1 ? WS_XS : seg == 2 ? WS_WQ
                     : seg == 3 ? WS_WK : seg == 4 ? WS_WV : (size_t)WS_WO;
    const int n4 = (seg < 2) ? 1048576 : 262144;  // float4 count
    ushort* d = ws + off;
    for (int i = blockIdx.x * 256 + threadIdx.x; i < n4; i += gridDim.x * 256) {
        float4 f = ((const float4*)src)[i];
        ushort4 u;
        u.x = f2bf(f.x); u.y = f2bf(f.y); u.z = f2bf(f.z); u.w = f2bf(f.w);
        ((ushort4*)d)[i] = u;
    }
}

// ---------------- qkv GEMM: 128x128 tile (unchanged, known-good) -------------
// grid (8, 32, 3): z = 0:Q, 1:K, 2:Vt
__global__ __launch_bounds__(256) void gemm128(
    const ushort* __restrict__ xtb, const ushort* __restrict__ xsb,
    const ushort* __restrict__ wqb, const ushort* __restrict__ wkb,
    const ushort* __restrict__ wvb,
    ushort* __restrict__ qh, ushort* __restrict__ kh, ushort* __restrict__ vt)
{
    __shared__ __align__(16) ushort SM[16384];

    const int mode = blockIdx.z;
    const ushort* Ap = (mode == 0) ? xtb : xsb;
    const ushort* Wp = (mode == 0) ? wqb : (mode == 1 ? wkb : wvb);

    const int tid  = threadIdx.x;
    const int wave = tid >> 6, lane = tid & 63;
    const int quad = lane >> 4, lidx = lane & 15;
    const int wm = wave >> 1, wn = wave & 1;
    const int m0 = blockIdx.y * 128, n0 = blockIdx.x * 128;

    const int slr = lane >> 2, scb = lane & 3;
    auto stage = [&](int k0, int bufi) {
        ushort* Asb = SM + bufi * 4096;
        ushort* Bsb = SM + 8192 + bufi * 4096;
#pragma unroll
        for (int i2 = 0; i2 < 2; ++i2) {
            const int i = wave + i2 * 4;
            const int r = i * 16 + slr;
            gld_lds16(Ap + (size_t)(m0 + r) * 1024 + k0 + scb * 8, Asb + i * 512);
            gld_lds16(Wp + (size_t)(n0 + r) * 1024 + k0 + scb * 8, Bsb + i * 512);
        }
    };

    f32x4 acc[4][4] = {};
    stage(0, 0);
    __syncthreads();

    for (int kt = 0; kt < 32; ++kt) {
        const int cur = kt & 1;
        if (kt < 31) stage((kt + 1) * 32, cur ^ 1);
        const ushort* Asb = SM + cur * 4096;
        const ushort* Bsb = SM + 8192 + cur * 4096;
        bf16x8 af[4], bfr[4];
#pragma unroll
        for (int i = 0; i < 4; ++i) {
            af[i]  = *(const bf16x8*)(Asb + (wm * 64 + i * 16 + lidx) * 32 + quad * 8);
            bfr[i] = *(const bf16x8*)(Bsb + (wn * 64 + i * 16 + lidx) * 32 + quad * 8);
        }
#pragma unroll
        for (int mi = 0; mi < 4; ++mi)
#pragma unroll
            for (int ni = 0; ni < 4; ++ni)
                acc[mi][ni] = MFMA(af[mi], bfr[ni], acc[mi][ni]);
        __syncthreads();
    }

    if (mode == 2) {
        ushort* scr = SM + wave * 4096;
#pragma unroll
        for (int mi = 0; mi < 4; ++mi)
#pragma unroll
            for (int ni = 0; ni < 4; ++ni)
#pragma unroll
                for (int r = 0; r < 4; ++r) {
                    const int dl = ni * 16 + lidx;
                    const int tl = mi * 16 + quad * 4 + r;
                    const int col = (((tl >> 3) ^ (dl & 7)) << 3) | (tl & 7);
                    scr[dl * 64 + col] = f2bf(acc[mi][ni][r]);
                }
        asm volatile("s_waitcnt lgkmcnt(0)" ::: "memory");
        const int hh = (n0 + wn * 64) >> 6;
        const int bb = m0 >> 11;
        const int t0 = (m0 + wm * 64) & 2047;
        ushort* Vtp = vt + (size_t)(bb * 16 + hh) * 64 * 2048;
#pragma unroll
        for (int ii = 0; ii < 8; ++ii) {
            const int dl = ii * 8 + (lane >> 3);
            const int tb = lane & 7;
            uint4 vd = *(const uint4*)(scr + dl * 64 + ((tb ^ (dl & 7)) << 3));
            *(uint4*)(Vtp + (size_t)dl * 2048 + t0 + tb * 8) = vd;
        }
        return;
    }

#pragma unroll
    for (int mi = 0; mi < 4; ++mi)
#pragma unroll
        for (int ni = 0; ni < 4; ++ni)
#pragma unroll
            for (int r = 0; r < 4; ++r) {
                const int m = m0 + wm * 64 + mi * 16 + quad * 4 + r;
                const int n = n0 + wn * 64 + ni * 16 + lidx;
                const int b = m >> 11, t = m & 2047;
                const int h = n >> 6,  d = n & 63;
                ushort* dst = (mode == 0) ? qh : kh;
                dst[((size_t)(b * 16 + h) * 2048 + t) * 64 + d] = f2bf(acc[mi][ni][r]);
            }
}

// ---------------- out GEMM: 128x64 tile, 512 blocks = 2/CU -------------------
__global__ __launch_bounds__(256) void gemm_out(
    const ushort* __restrict__ aob, const ushort* __restrict__ wob,
    const float* __restrict__ bias, float* __restrict__ outf)
{
    __shared__ __align__(16) ushort SM[12288];

    const int tid  = threadIdx.x;
    const int wave = tid >> 6, lane = tid & 63;
    const int quad = lane >> 4, lidx = lane & 15;
    const int m0 = blockIdx.y * 128, n0 = blockIdx.x * 64;

    const int slr = lane >> 2, scb = lane & 3;
    auto stage = [&](int k0, int bufi) {
        ushort* Asb = SM + bufi * 4096;
        ushort* Bsb = SM + 8192 + bufi * 2048;
#pragma unroll
        for (int i2 = 0; i2 < 2; ++i2) {
            const int i = wave * 2 + i2;
            gld_lds16(aob + (size_t)(m0 + i * 16 + slr) * 1024 + k0 + scb * 8,
                      Asb + i * 512);
        }
        gld_lds16(wob + (size_t)(n0 + wave * 16 + slr) * 1024 + k0 + scb * 8,
                  Bsb + wave * 512);
    };

    f32x4 acc[2][4] = {};
    stage(0, 0);
    __syncthreads();

    for (int kt = 0; kt < 32; ++kt) {
        const int cur = kt & 1;
        if (kt < 31) stage((kt + 1) * 32, cur ^ 1);
        const ushort* Asb = SM + cur * 4096;
        const ushort* Bsb = SM + 8192 + cur * 2048;
        bf16x8 af[2], bfr[4];
#pragma unroll
        for (int i = 0; i < 2; ++i)
            af[i] = *(const bf16x8*)(Asb + (wave * 32 + i * 16 + lidx) * 32 + quad * 8);
#pragma unroll
        for (int i = 0; i < 4; ++i)
            bfr[i] = *(const bf16x8*)(Bsb + (i * 16 + lidx) * 32 + quad * 8);
#pragma unroll
        for (int mi = 0; mi < 2; ++mi)
#pragma unroll
            for (int ni = 0; ni < 4; ++ni)
                acc[mi][ni] = MFMA(af[mi], bfr[ni], acc[mi][ni]);
        __syncthreads();
    }

#pragma unroll
    for (int mi = 0; mi < 2; ++mi)
#pragma unroll
        for (int ni = 0; ni < 4; ++ni)
#pragma unroll
            for (int r = 0; r < 4; ++r) {
                const int m = m0 + wave * 32 + mi * 16 + quad * 4 + r;
                const int n = n0 + ni * 16 + lidx;
                outf[(size_t)m * 1024 + n] = acc[mi][ni][r] + bias[n];
            }
}

// ---------------- flash_attn v5: 256 Q-rows/block, 8 waves x 2 subtiles ------
// grid (8, 32), 512 thr, 1 block/CU. K/V frag reads amortized over 2 subtiles
// (32 MFMA per 16 K/V b128 reads) -> LDS-cycle model 4640 -> 3104 per CU-iter.
__global__ __launch_bounds__(512) void flash_attn(
    const ushort* __restrict__ Qh, const ushort* __restrict__ Kh,
    const ushort* __restrict__ Vt, ushort* __restrict__ AO)
{
    __shared__ __align__(16) ushort Kb[2][4096];   // [buf][chunk*512 + slot]
    __shared__ __align__(16) ushort Vb[2][4096];
    __shared__ __align__(16) ushort P[8][16][LDP]; // wave-private, per-subtile reuse

    const int tid  = threadIdx.x;
    const int wave = tid >> 6, lane = tid & 63;
    const int quad = lane >> 4, lidx = lane & 15;
    const int bh = blockIdx.y;
    const int b = bh >> 4, h = bh & 15;
    const int qbase = blockIdx.x * 256 + wave * 32;

    const ushort* Qp = Qh + (size_t)bh * 2048 * 64;
    const ushort* Kp = Kh + (size_t)bh * 2048 * 64;
    const ushort* Vp = Vt + (size_t)bh * 64 * 2048;

    // Q fragments (2 subtiles x 16 rows), prescaled by (1/8)*log2(e)
    bf16x8 q[2][2];
#pragma unroll
    for (int t = 0; t < 2; ++t) {
        const ushort* qr = Qp + (size_t)(qbase + t * 16 + lidx) * 64 + quad * 8;
        union { ushort u[8]; uint4 v; } t0, t1;
        t0.v = *(const uint4*)qr;
        t1.v = *(const uint4*)(qr + 32);
#pragma unroll
        for (int i = 0; i < 8; ++i) {
            ((short*)&q[t][0])[i] = (short)f2bf(bf2f(t0.u[i]) * 0.18033688f);
            ((short*)&q[t][1])[i] = (short)f2bf(bf2f(t1.u[i]) * 0.18033688f);
        }
    }

    // staging: wave w stages chunk w (rows w*8..w*8+7): 1 K-gld + 1 V-gld
    auto stage = [&](int s0, int bufi) {
        const int slot = wave * 64 + lane;       // 0..511
        const int r  = slot >> 3;
        const int bb = slot & 7;
        const int gb = bb ^ (r & 7);
        gld_lds16(Kp + (size_t)(s0 + r) * 64 + gb * 8, &Kb[bufi][wave * 512]);
        gld_lds16(Vp + (size_t)r * 2048 + s0 + gb * 8, &Vb[bufi][wave * 512]);
    };

    float lsum[2][4] = {};
    f32x4 o[2][4] = {};

    stage(0, 0);
    __syncthreads();

    for (int j = 0; j < 32; ++j) {
        const int cur = j & 1;
        stage(((j + 1) & 31) * 64, cur ^ 1);

        // QK^T: K frags shared across both subtiles
        f32x4 s[2][4] = {};
#pragma unroll
        for (int n0 = 0; n0 < 4; ++n0) {
            const int row = n0 * 16 + lidx;
            bf16x8 k0 = *(const bf16x8*)&Kb[cur][row * 64 + ((quad ^ (row & 7)) * 8)];
            bf16x8 k1 = *(const bf16x8*)&Kb[cur][row * 64 + (((4 + quad) ^ (row & 7)) * 8)];
#pragma unroll
            for (int t = 0; t < 2; ++t) {
                s[t][n0] = MFMA(q[t][0], k0, s[t][n0]);
                s[t][n0] = MFMA(q[t][1], k1, s[t][n0]);
            }
        }

        // unnormalized softmax, P round-trip per subtile (DS in-order per wave)
        bf16x8 pf[2][2];
#pragma unroll
        for (int t = 0; t < 2; ++t) {
#pragma unroll
            for (int n0 = 0; n0 < 4; ++n0)
#pragma unroll
                for (int r = 0; r < 4; r += 2) {
                    const float pa = __builtin_amdgcn_exp2f(s[t][n0][r]);
                    const float pb = __builtin_amdgcn_exp2f(s[t][n0][r + 1]);
                    lsum[t][r] += pa;
                    lsum[t][r + 1] += pb;
                    const ushort2 u2 = pk2bf(pa, pb);
                    P[wave][quad * 4 + r][n0 * 16 + lidx] = u2.x;
                    P[wave][quad * 4 + r + 1][n0 * 16 + lidx] = u2.y;
                }
            asm volatile("s_waitcnt lgkmcnt(0)" ::: "memory");
            pf[t][0] = *(const bf16x8*)&P[wave][lidx][quad * 8];
            pf[t][1] = *(const bf16x8*)&P[wave][lidx][32 + quad * 8];
        }

        // P @ V: V frags shared across both subtiles
#pragma unroll
        for (int n0 = 0; n0 < 4; ++n0) {
            const int d = n0 * 16 + lidx;
            bf16x8 v0 = *(const bf16x8*)&Vb[cur][d * 64 + ((quad ^ (d & 7)) * 8)];
            bf16x8 v1 = *(const bf16x8*)&Vb[cur][d * 64 + (((4 + quad) ^ (d & 7)) * 8)];
#pragma unroll
            for (int t = 0; t < 2; ++t) {
                o[t][n0] = MFMA(pf[t][0], v0, o[t][n0]);
                o[t][n0] = MFMA(pf[t][1], v1, o[t][n0]);
            }
        }
        __syncthreads();
    }

#pragma unroll
    for (int t = 0; t < 2; ++t)
#pragma unroll
        for (int r = 0; r < 4; ++r) {
            float v = lsum[t][r];
            v += __shfl_xor(v, 1);
            v += __shfl_xor(v, 2);
            v += __shfl_xor(v, 4);
            v += __shfl_xor(v, 8);
            lsum[t][r] = v;
        }

#pragma unroll
    for (int t = 0; t < 2; ++t)
#pragma unroll
        for (int n0 = 0; n0 < 4; ++n0)
#pragma unroll
            for (int r = 0; r < 4; r += 2) {
                const int tt = qbase + t * 16 + quad * 4 + r;
                const int d  = n0 * 16 + lidx;
                const ushort2 u2 = pk2bf(o[t][n0][r] / lsum[t][r],
                                         o[t][n0][r + 1] / lsum[t][r + 1]);
                AO[(size_t)(b * 2048 + tt) * 1024 + h * 64 + d] = u2.x;
                AO[(size_t)(b * 2048 + tt + 1) * 1024 + h * 64 + d] = u2.y;
            }
}

extern "C" void kernel_launch(void* const* d_in, const int* in_sizes, int n_in,
                              void* d_out, int out_size, void* d_ws, size_t ws_size,
                              hipStream_t stream) {
    const float* xt = (const float*)d_in[0];
    const float* xs = (const float*)d_in[1];
    const float* Wq = (const float*)d_in[2];
    const float* Wk = (const float*)d_in[3];
    const float* Wv = (const float*)d_in[4];
    const float* Wo = (const float*)d_in[5];
    const float* bo = (const float*)d_in[6];
    float* out = (float*)d_out;

    ushort* ws = (ushort*)d_ws;

    cast_bf16<<<dim3(1024, 6, 1), 256, 0, stream>>>(xt, xs, Wq, Wk, Wv, Wo, ws);

    gemm128<<<dim3(8, 32, 3), 256, 0, stream>>>(
        ws + WS_XT, ws + WS_XS, ws + WS_WQ, ws + WS_WK, ws + WS_WV,
        ws + WS_QH, ws + WS_KH, ws + WS_VT);

    flash_attn<<<dim3(8, 32, 1), 512, 0, stream>>>(
        ws + WS_QH, ws + WS_KH, ws + WS_VT, ws + WS_AO);

    gemm_out<<<dim3(16, 32, 1), 256, 0, stream>>>(
        ws + WS_AO, ws + WS_WO, bo, out);
}

// Round 9
// 212.690 us; speedup vs baseline: 1.0382x; 1.0382x over previous
//
#include <hip/hip_runtime.h>
#include <hip/hip_bf16.h>

typedef short bf16x8 __attribute__((ext_vector_type(8)));
typedef float f32x4 __attribute__((ext_vector_type(4)));

#define LDP 72  // flash P row stride

__device__ __forceinline__ float bf2f(ushort u) {
    union { unsigned int i; float f; } v; v.i = ((unsigned int)u) << 16; return v.f;
}
__device__ __forceinline__ ushort f2bf(float f) {
    union { float f; unsigned int i; } v; v.f = f;
    unsigned int x = v.i;
    x += 0x7fffu + ((x >> 16) & 1u);  // RNE (finite values only)
    return (ushort)(x >> 16);
}
// packed 2x f32->bf16 (v_cvt_pk_bf16_f32 on gfx950), RNE
__device__ __forceinline__ ushort2 pk2bf(float a, float b) {
    union { __hip_bfloat162 h2; ushort2 u2; } cv;
    cv.h2 = __float22bfloat162_rn(float2{a, b});
    return cv.u2;
}

#define MFMA(a, b, c) __builtin_amdgcn_mfma_f32_16x16x32_bf16(a, b, c, 0, 0, 0)

// fine-grained barrier: wait for all but the newest N vmem ops, then s_barrier.
// Avoids __syncthreads' vmcnt(0) drain that stalls on the in-flight prefetch.
#define WAIT_BARRIER(N) asm volatile("s_waitcnt vmcnt(" #N ")\n\ts_barrier" ::: "memory")

// async global->LDS, 16B/lane; LDS dest = wave-uniform base + lane*16
__device__ __forceinline__ void gld_lds16(const ushort* g, ushort* l) {
    __builtin_amdgcn_global_load_lds(
        (const __attribute__((address_space(1))) unsigned int*)g,
        (__attribute__((address_space(3))) unsigned int*)l, 16, 0, 0);
}

// ws layout (ushort elems)
#define WS_XT 0
#define WS_XS 4194304
#define WS_WQ 8388608
#define WS_WK 9437184
#define WS_WV 10485760
#define WS_WO 11534336
#define WS_QH 12582912
#define WS_KH 16777216
#define WS_VT 20971520
#define WS_AO 0   // reuses XT region (XT dead after qkv_gemm)

// ---------------- cast: fp32 -> bf16 into ws ----------------
__global__ __launch_bounds__(256) void cast_bf16(
    const float* __restrict__ s0, const float* __restrict__ s1,
    const float* __restrict__ s2, const float* __restrict__ s3,
    const float* __restrict__ s4, const float* __restrict__ s5,
    ushort* __restrict__ ws)
{
    const int seg = blockIdx.y;
    const float* src = seg == 0 ? s0 : seg == 1 ? s1 : seg == 2 ? s2
                     : seg == 3 ? s3 : seg == 4 ? s4 : s5;
    const size_t off = seg == 0 ? WS_XT : seg == 1 ? WS_XS : seg == 2 ? WS_WQ
                     : seg == 3 ? WS_WK : seg == 4 ? WS_WV : (size_t)WS_WO;
    const int n4 = (seg < 2) ? 1048576 : 262144;  // float4 count
    ushort* d = ws + off;
    for (int i = blockIdx.x * 256 + threadIdx.x; i < n4; i += gridDim.x * 256) {
        float4 f = ((const float4*)src)[i];
        ushort4 u;
        u.x = f2bf(f.x); u.y = f2bf(f.y); u.z = f2bf(f.z); u.w = f2bf(f.w);
        ((ushort4*)d)[i] = u;
    }
}

// ---------------- qkv GEMM: 128x128 tile, triple-buffered fine-vmcnt ---------
// grid (8, 32, 3): z = 0:Q, 1:K, 2:Vt.  4 gld/wave/iter -> vmcnt(4).
__global__ __launch_bounds__(256) void gemm128(
    const ushort* __restrict__ xtb, const ushort* __restrict__ xsb,
    const ushort* __restrict__ wqb, const ushort* __restrict__ wkb,
    const ushort* __restrict__ wvb,
    ushort* __restrict__ qh, ushort* __restrict__ kh, ushort* __restrict__ vt)
{
    __shared__ __align__(16) ushort SM[24576];  // A: 3x4096, B: 12288 + 3x4096

    const int mode = blockIdx.z;
    const ushort* Ap = (mode == 0) ? xtb : xsb;
    const ushort* Wp = (mode == 0) ? wqb : (mode == 1 ? wkb : wvb);

    const int tid  = threadIdx.x;
    const int wave = tid >> 6, lane = tid & 63;
    const int quad = lane >> 4, lidx = lane & 15;
    const int wm = wave >> 1, wn = wave & 1;
    const int m0 = blockIdx.y * 128, n0 = blockIdx.x * 128;

    const int slr = lane >> 2, scb = lane & 3;
    auto stage = [&](int k0, int bufi) {
        ushort* Asb = SM + bufi * 4096;
        ushort* Bsb = SM + 12288 + bufi * 4096;
#pragma unroll
        for (int i2 = 0; i2 < 2; ++i2) {
            const int i = wave + i2 * 4;
            const int r = i * 16 + slr;
            gld_lds16(Ap + (size_t)(m0 + r) * 1024 + k0 + scb * 8, Asb + i * 512);
            gld_lds16(Wp + (size_t)(n0 + r) * 1024 + k0 + scb * 8, Bsb + i * 512);
        }
    };

    f32x4 acc[4][4] = {};
    stage(0, 0);
    stage(32, 1);

    for (int kt = 0; kt < 32; ++kt) {
        const int cur = kt % 3;
        WAIT_BARRIER(4);  // my buf-kt DMAs retired; all waves done reading kt-1
        stage(((kt + 2) & 31) * 32, (kt + 2) % 3);  // wrap: keeps vmcnt invariant
        const ushort* Asb = SM + cur * 4096;
        const ushort* Bsb = SM + 12288 + cur * 4096;
        bf16x8 af[4], bfr[4];
#pragma unroll
        for (int i = 0; i < 4; ++i) {
            af[i]  = *(const bf16x8*)(Asb + (wm * 64 + i * 16 + lidx) * 32 + quad * 8);
            bfr[i] = *(const bf16x8*)(Bsb + (wn * 64 + i * 16 + lidx) * 32 + quad * 8);
        }
#pragma unroll
        for (int mi = 0; mi < 4; ++mi)
#pragma unroll
            for (int ni = 0; ni < 4; ++ni)
                acc[mi][ni] = MFMA(af[mi], bfr[ni], acc[mi][ni]);
    }
    __syncthreads();  // full drain once: epilogue may reuse SM as scratch

    if (mode == 2) {
        ushort* scr = SM + wave * 4096;
#pragma unroll
        for (int mi = 0; mi < 4; ++mi)
#pragma unroll
            for (int ni = 0; ni < 4; ++ni)
#pragma unroll
                for (int r = 0; r < 4; ++r) {
                    const int dl = ni * 16 + lidx;
                    const int tl = mi * 16 + quad * 4 + r;
                    const int col = (((tl >> 3) ^ (dl & 7)) << 3) | (tl & 7);
                    scr[dl * 64 + col] = f2bf(acc[mi][ni][r]);
                }
        asm volatile("s_waitcnt lgkmcnt(0)" ::: "memory");
        const int hh = (n0 + wn * 64) >> 6;
        const int bb = m0 >> 11;
        const int t0 = (m0 + wm * 64) & 2047;
        ushort* Vtp = vt + (size_t)(bb * 16 + hh) * 64 * 2048;
#pragma unroll
        for (int ii = 0; ii < 8; ++ii) {
            const int dl = ii * 8 + (lane >> 3);
            const int tb = lane & 7;
            uint4 vd = *(const uint4*)(scr + dl * 64 + ((tb ^ (dl & 7)) << 3));
            *(uint4*)(Vtp + (size_t)dl * 2048 + t0 + tb * 8) = vd;
        }
        return;
    }

#pragma unroll
    for (int mi = 0; mi < 4; ++mi)
#pragma unroll
        for (int ni = 0; ni < 4; ++ni)
#pragma unroll
            for (int r = 0; r < 4; ++r) {
                const int m = m0 + wm * 64 + mi * 16 + quad * 4 + r;
                const int n = n0 + wn * 64 + ni * 16 + lidx;
                const int b = m >> 11, t = m & 2047;
                const int h = n >> 6,  d = n & 63;
                ushort* dst = (mode == 0) ? qh : kh;
                dst[((size_t)(b * 16 + h) * 2048 + t) * 64 + d] = f2bf(acc[mi][ni][r]);
            }
}

// ---------------- out GEMM: 128x64 tile, triple-buffered fine-vmcnt ----------
// 3 gld/wave/iter -> vmcnt(3). 512 blocks = 2/CU.
__global__ __launch_bounds__(256) void gemm_out(
    const ushort* __restrict__ aob, const ushort* __restrict__ wob,
    const float* __restrict__ bias, float* __restrict__ outf)
{
    __shared__ __align__(16) ushort SM[18432];  // A: 3x4096, B: 12288 + 3x2048

    const int tid  = threadIdx.x;
    const int wave = tid >> 6, lane = tid & 63;
    const int quad = lane >> 4, lidx = lane & 15;
    const int m0 = blockIdx.y * 128, n0 = blockIdx.x * 64;

    const int slr = lane >> 2, scb = lane & 3;
    auto stage = [&](int k0, int bufi) {
        ushort* Asb = SM + bufi * 4096;
        ushort* Bsb = SM + 12288 + bufi * 2048;
#pragma unroll
        for (int i2 = 0; i2 < 2; ++i2) {
            const int i = wave * 2 + i2;
            gld_lds16(aob + (size_t)(m0 + i * 16 + slr) * 1024 + k0 + scb * 8,
                      Asb + i * 512);
        }
        gld_lds16(wob + (size_t)(n0 + wave * 16 + slr) * 1024 + k0 + scb * 8,
                  Bsb + wave * 512);
    };

    f32x4 acc[2][4] = {};
    stage(0, 0);
    stage(32, 1);

    for (int kt = 0; kt < 32; ++kt) {
        const int cur = kt % 3;
        WAIT_BARRIER(3);
        stage(((kt + 2) & 31) * 32, (kt + 2) % 3);
        const ushort* Asb = SM + cur * 4096;
        const ushort* Bsb = SM + 12288 + cur * 2048;
        bf16x8 af[2], bfr[4];
#pragma unroll
        for (int i = 0; i < 2; ++i)
            af[i] = *(const bf16x8*)(Asb + (wave * 32 + i * 16 + lidx) * 32 + quad * 8);
#pragma unroll
        for (int i = 0; i < 4; ++i)
            bfr[i] = *(const bf16x8*)(Bsb + (i * 16 + lidx) * 32 + quad * 8);
#pragma unroll
        for (int mi = 0; mi < 2; ++mi)
#pragma unroll
            for (int ni = 0; ni < 4; ++ni)
                acc[mi][ni] = MFMA(af[mi], bfr[ni], acc[mi][ni]);
    }

#pragma unroll
    for (int mi = 0; mi < 2; ++mi)
#pragma unroll
        for (int ni = 0; ni < 4; ++ni)
#pragma unroll
            for (int r = 0; r < 4; ++r) {
                const int m = m0 + wave * 32 + mi * 16 + quad * 4 + r;
                const int n = n0 + ni * 16 + lidx;
                outf[(size_t)m * 1024 + n] = acc[mi][ni][r] + bias[n];
            }
}

// ---------------- flash_attn v6: v5 + triple-buffer fine-vmcnt ---------------
// grid (8, 32), 512 thr. 2 gld/wave/iter -> vmcnt(2).
__global__ __launch_bounds__(512) void flash_attn(
    const ushort* __restrict__ Qh, const ushort* __restrict__ Kh,
    const ushort* __restrict__ Vt, ushort* __restrict__ AO)
{
    __shared__ __align__(16) ushort Kb[3][4096];
    __shared__ __align__(16) ushort Vb[3][4096];
    __shared__ __align__(16) ushort P[8][16][LDP];

    const int tid  = threadIdx.x;
    const int wave = tid >> 6, lane = tid & 63;
    const int quad = lane >> 4, lidx = lane & 15;
    const int bh = blockIdx.y;
    const int b = bh >> 4, h = bh & 15;
    const int qbase = blockIdx.x * 256 + wave * 32;

    const ushort* Qp = Qh + (size_t)bh * 2048 * 64;
    const ushort* Kp = Kh + (size_t)bh * 2048 * 64;
    const ushort* Vp = Vt + (size_t)bh * 64 * 2048;

    // Q fragments (2 subtiles x 16 rows), prescaled by (1/8)*log2(e)
    bf16x8 q[2][2];
#pragma unroll
    for (int t = 0; t < 2; ++t) {
        const ushort* qr = Qp + (size_t)(qbase + t * 16 + lidx) * 64 + quad * 8;
        union { ushort u[8]; uint4 v; } t0, t1;
        t0.v = *(const uint4*)qr;
        t1.v = *(const uint4*)(qr + 32);
#pragma unroll
        for (int i = 0; i < 8; ++i) {
            ((short*)&q[t][0])[i] = (short)f2bf(bf2f(t0.u[i]) * 0.18033688f);
            ((short*)&q[t][1])[i] = (short)f2bf(bf2f(t1.u[i]) * 0.18033688f);
        }
    }

    // staging: wave w stages chunk w (rows w*8..w*8+7): 1 K-gld + 1 V-gld
    auto stage = [&](int s0, int bufi) {
        const int slot = wave * 64 + lane;       // 0..511
        const int r  = slot >> 3;
        const int bb = slot & 7;
        const int gb = bb ^ (r & 7);
        gld_lds16(Kp + (size_t)(s0 + r) * 64 + gb * 8, &Kb[bufi][wave * 512]);
        gld_lds16(Vp + (size_t)r * 2048 + s0 + gb * 8, &Vb[bufi][wave * 512]);
    };

    float lsum[2][4] = {};
    f32x4 o[2][4] = {};

    stage(0, 0);
    stage(64, 1);

    for (int j = 0; j < 32; ++j) {
        const int cur = j % 3;
        WAIT_BARRIER(2);
        stage(((j + 2) & 31) * 64, (j + 2) % 3);

        // QK^T: K frags shared across both subtiles
        f32x4 s[2][4] = {};
#pragma unroll
        for (int n0 = 0; n0 < 4; ++n0) {
            const int row = n0 * 16 + lidx;
            bf16x8 k0 = *(const bf16x8*)&Kb[cur][row * 64 + ((quad ^ (row & 7)) * 8)];
            bf16x8 k1 = *(const bf16x8*)&Kb[cur][row * 64 + (((4 + quad) ^ (row & 7)) * 8)];
#pragma unroll
            for (int t = 0; t < 2; ++t) {
                s[t][n0] = MFMA(q[t][0], k0, s[t][n0]);
                s[t][n0] = MFMA(q[t][1], k1, s[t][n0]);
            }
        }

        // unnormalized softmax, P round-trip per subtile (DS in-order per wave)
        bf16x8 pf[2][2];
#pragma unroll
        for (int t = 0; t < 2; ++t) {
#pragma unroll
            for (int n0 = 0; n0 < 4; ++n0)
#pragma unroll
                for (int r = 0; r < 4; r += 2) {
                    const float pa = __builtin_amdgcn_exp2f(s[t][n0][r]);
                    const float pb = __builtin_amdgcn_exp2f(s[t][n0][r + 1]);
                    lsum[t][r] += pa;
                    lsum[t][r + 1] += pb;
                    const ushort2 u2 = pk2bf(pa, pb);
                    P[wave][quad * 4 + r][n0 * 16 + lidx] = u2.x;
                    P[wave][quad * 4 + r + 1][n0 * 16 + lidx] = u2.y;
                }
            asm volatile("s_waitcnt lgkmcnt(0)" ::: "memory");
            pf[t][0] = *(const bf16x8*)&P[wave][lidx][quad * 8];
            pf[t][1] = *(const bf16x8*)&P[wave][lidx][32 + quad * 8];
        }

        // P @ V: V frags shared across both subtiles
#pragma unroll
        for (int n0 = 0; n0 < 4; ++n0) {
            const int d = n0 * 16 + lidx;
            bf16x8 v0 = *(const bf16x8*)&Vb[cur][d * 64 + ((quad ^ (d & 7)) * 8)];
            bf16x8 v1 = *(const bf16x8*)&Vb[cur][d * 64 + (((4 + quad) ^ (d & 7)) * 8)];
#pragma unroll
            for (int t = 0; t < 2; ++t) {
                o[t][n0] = MFMA(pf[t][0], v0, o[t][n0]);
                o[t][n0] = MFMA(pf[t][1], v1, o[t][n0]);
            }
        }
    }

#pragma unroll
    for (int t = 0; t < 2; ++t)
#pragma unroll
        for (int r = 0; r < 4; ++r) {
            float v = lsum[t][r];
            v += __shfl_xor(v, 1);
            v += __shfl_xor(v, 2);
            v += __shfl_xor(v, 4);
            v += __shfl_xor(v, 8);
            lsum[t][r] = v;
        }

#pragma unroll
    for (int t = 0; t < 2; ++t)
#pragma unroll
        for (int n0 = 0; n0 < 4; ++n0)
#pragma unroll
            for (int r = 0; r < 4; r += 2) {
                const int tt = qbase + t * 16 + quad * 4 + r;
                const int d  = n0 * 16 + lidx;
                const ushort2 u2 = pk2bf(o[t][n0][r] / lsum[t][r],
                                         o[t][n0][r + 1] / lsum[t][r + 1]);
                AO[(size_t)(b * 2048 + tt) * 1024 + h * 64 + d] = u2.x;
                AO[(size_t)(b * 2048 + tt + 1) * 1024 + h * 64 + d] = u2.y;
            }
}

extern "C" void kernel_launch(void* const* d_in, const int* in_sizes, int n_in,
                              void* d_out, int out_size, void* d_ws, size_t ws_size,
                              hipStream_t stream) {
    const float* xt = (const float*)d_in[0];
    const float* xs = (const float*)d_in[1];
    const float* Wq = (const float*)d_in[2];
    const float* Wk = (const float*)d_in[3];
    const float* Wv = (const float*)d_in[4];
    const float* Wo = (const float*)d_in[5];
    const float* bo = (const float*)d_in[6];
    float* out = (float*)d_out;

    ushort* ws = (ushort*)d_ws;

    cast_bf16<<<dim3(1024, 6, 1), 256, 0, stream>>>(xt, xs, Wq, Wk, Wv, Wo, ws);

    gemm128<<<dim3(8, 32, 3), 256, 0, stream>>>(
        ws + WS_XT, ws + WS_XS, ws + WS_WQ, ws + WS_WK, ws + WS_WV,
        ws + WS_QH, ws + WS_KH, ws + WS_VT);

    flash_attn<<<dim3(8, 32, 1), 512, 0, stream>>>(
        ws + WS_QH, ws + WS_KH, ws + WS_VT, ws + WS_AO);

    gemm_out<<<dim3(16, 32, 1), 256, 0, stream>>>(
        ws + WS_AO, ws + WS_WO, bo, out);
}

// Round 10
// 211.311 us; speedup vs baseline: 1.0450x; 1.0065x over previous
//
#include <hip/hip_runtime.h>
#include <hip/hip_bf16.h>

typedef short bf16x8 __attribute__((ext_vector_type(8)));
typedef float f32x4 __attribute__((ext_vector_type(4)));

#define LDP 72  // flash P row stride

__device__ __forceinline__ float bf2f(ushort u) {
    union { unsigned int i; float f; } v; v.i = ((unsigned int)u) << 16; return v.f;
}
__device__ __forceinline__ ushort f2bf(float f) {
    union { float f; unsigned int i; } v; v.f = f;
    unsigned int x = v.i;
    x += 0x7fffu + ((x >> 16) & 1u);  // RNE (finite values only)
    return (ushort)(x >> 16);
}
// packed 2x f32->bf16 (v_cvt_pk_bf16_f32 on gfx950), RNE
__device__ __forceinline__ ushort2 pk2bf(float a, float b) {
    union { __hip_bfloat162 h2; ushort2 u2; } cv;
    cv.h2 = __float22bfloat162_rn(float2{a, b});
    return cv.u2;
}

#define MFMA(a, b, c) __builtin_amdgcn_mfma_f32_16x16x32_bf16(a, b, c, 0, 0, 0)

// fine-grained barrier: wait for all but the newest N vmem ops, then s_barrier.
#define WAIT_BARRIER(N) asm volatile("s_waitcnt vmcnt(" #N ")\n\ts_barrier" ::: "memory")

// async global->LDS, 16B/lane; LDS dest = wave-uniform base + lane*16
__device__ __forceinline__ void gld_lds16(const ushort* g, ushort* l) {
    __builtin_amdgcn_global_load_lds(
        (const __attribute__((address_space(1))) unsigned int*)g,
        (__attribute__((address_space(3))) unsigned int*)l, 16, 0, 0);
}

// ws layout (ushort elems)
#define WS_XT 0
#define WS_XS 4194304
#define WS_WQ 8388608
#define WS_WK 9437184
#define WS_WV 10485760
#define WS_WO 11534336
#define WS_QH 12582912
#define WS_KH 16777216
#define WS_VT 20971520
#define WS_AO 0   // reuses XT region (XT dead after qkv_gemm)

// ---------------- cast: fp32 -> bf16 into ws (unchanged R8) ----------------
__global__ __launch_bounds__(256) void cast_bf16(
    const float* __restrict__ s0, const float* __restrict__ s1,
    const float* __restrict__ s2, const float* __restrict__ s3,
    const float* __restrict__ s4, const float* __restrict__ s5,
    ushort* __restrict__ ws)
{
    const int seg = blockIdx.y;
    const float* src = seg == 0 ? s0 : seg == 1 ? s1 : seg == 2 ? s2
                     : seg == 3 ? s3 : seg == 4 ? s4 : s5;
    const size_t off = seg == 0 ? WS_XT : seg == 1 ? WS_XS : seg == 2 ? WS_WQ
                     : seg == 3 ? WS_WK : seg == 4 ? WS_WV : (size_t)WS_WO;
    const int n4 = (seg < 2) ? 1048576 : 262144;  // float4 count
    ushort* d = ws + off;
    for (int i = blockIdx.x * 256 + threadIdx.x; i < n4; i += gridDim.x * 256) {
        float4 f = ((const float4*)src)[i];
        ushort4 u;
        u.x = f2bf(f.x); u.y = f2bf(f.y); u.z = f2bf(f.z); u.w = f2bf(f.w);
        ((ushort4*)d)[i] = u;
    }
}

// ---------------- qkv GEMM: 128x128 tile, tri-buffer fine-vmcnt (R8 win) -----
__global__ __launch_bounds__(256) void gemm128(
    const ushort* __restrict__ xtb, const ushort* __restrict__ xsb,
    const ushort* __restrict__ wqb, const ushort* __restrict__ wkb,
    const ushort* __restrict__ wvb,
    ushort* __restrict__ qh, ushort* __restrict__ kh, ushort* __restrict__ vt)
{
    __shared__ __align__(16) ushort SM[24576];  // A: 3x4096, B: 12288 + 3x4096

    const int mode = blockIdx.z;
    const ushort* Ap = (mode == 0) ? xtb : xsb;
    const ushort* Wp = (mode == 0) ? wqb : (mode == 1 ? wkb : wvb);

    const int tid  = threadIdx.x;
    const int wave = tid >> 6, lane = tid & 63;
    const int quad = lane >> 4, lidx = lane & 15;
    const int wm = wave >> 1, wn = wave & 1;
    const int m0 = blockIdx.y * 128, n0 = blockIdx.x * 128;

    const int slr = lane >> 2, scb = lane & 3;
    auto stage = [&](int k0, int bufi) {
        ushort* Asb = SM + bufi * 4096;
        ushort* Bsb = SM + 12288 + bufi * 4096;
#pragma unroll
        for (int i2 = 0; i2 < 2; ++i2) {
            const int i = wave + i2 * 4;
            const int r = i * 16 + slr;
            gld_lds16(Ap + (size_t)(m0 + r) * 1024 + k0 + scb * 8, Asb + i * 512);
            gld_lds16(Wp + (size_t)(n0 + r) * 1024 + k0 + scb * 8, Bsb + i * 512);
        }
    };

    f32x4 acc[4][4] = {};
    stage(0, 0);
    stage(32, 1);

    for (int kt = 0; kt < 32; ++kt) {
        const int cur = kt % 3;
        WAIT_BARRIER(4);
        stage(((kt + 2) & 31) * 32, (kt + 2) % 3);
        const ushort* Asb = SM + cur * 4096;
        const ushort* Bsb = SM + 12288 + cur * 4096;
        bf16x8 af[4], bfr[4];
#pragma unroll
        for (int i = 0; i < 4; ++i) {
            af[i]  = *(const bf16x8*)(Asb + (wm * 64 + i * 16 + lidx) * 32 + quad * 8);
            bfr[i] = *(const bf16x8*)(Bsb + (wn * 64 + i * 16 + lidx) * 32 + quad * 8);
        }
#pragma unroll
        for (int mi = 0; mi < 4; ++mi)
#pragma unroll
            for (int ni = 0; ni < 4; ++ni)
                acc[mi][ni] = MFMA(af[mi], bfr[ni], acc[mi][ni]);
    }
    __syncthreads();  // full drain once: epilogue may reuse SM as scratch

    if (mode == 2) {
        ushort* scr = SM + wave * 4096;
#pragma unroll
        for (int mi = 0; mi < 4; ++mi)
#pragma unroll
            for (int ni = 0; ni < 4; ++ni)
#pragma unroll
                for (int r = 0; r < 4; ++r) {
                    const int dl = ni * 16 + lidx;
                    const int tl = mi * 16 + quad * 4 + r;
                    const int col = (((tl >> 3) ^ (dl & 7)) << 3) | (tl & 7);
                    scr[dl * 64 + col] = f2bf(acc[mi][ni][r]);
                }
        asm volatile("s_waitcnt lgkmcnt(0)" ::: "memory");
        const int hh = (n0 + wn * 64) >> 6;
        const int bb = m0 >> 11;
        const int t0 = (m0 + wm * 64) & 2047;
        ushort* Vtp = vt + (size_t)(bb * 16 + hh) * 64 * 2048;
#pragma unroll
        for (int ii = 0; ii < 8; ++ii) {
            const int dl = ii * 8 + (lane >> 3);
            const int tb = lane & 7;
            uint4 vd = *(const uint4*)(scr + dl * 64 + ((tb ^ (dl & 7)) << 3));
            *(uint4*)(Vtp + (size_t)dl * 2048 + t0 + tb * 8) = vd;
        }
        return;
    }

#pragma unroll
    for (int mi = 0; mi < 4; ++mi)
#pragma unroll
        for (int ni = 0; ni < 4; ++ni)
#pragma unroll
            for (int r = 0; r < 4; ++r) {
                const int m = m0 + wm * 64 + mi * 16 + quad * 4 + r;
                const int n = n0 + wn * 64 + ni * 16 + lidx;
                const int b = m >> 11, t = m & 2047;
                const int h = n >> 6,  d = n & 63;
                ushort* dst = (mode == 0) ? qh : kh;
                dst[((size_t)(b * 16 + h) * 2048 + t) * 64 + d] = f2bf(acc[mi][ni][r]);
            }
}

// ---------------- out GEMM: 128x64 tile, tri-buffer fine-vmcnt (R8 win) ------
__global__ __launch_bounds__(256) void gemm_out(
    const ushort* __restrict__ aob, const ushort* __restrict__ wob,
    const float* __restrict__ bias, float* __restrict__ outf)
{
    __shared__ __align__(16) ushort SM[18432];

    const int tid  = threadIdx.x;
    const int wave = tid >> 6, lane = tid & 63;
    const int quad = lane >> 4, lidx = lane & 15;
    const int m0 = blockIdx.y * 128, n0 = blockIdx.x * 64;

    const int slr = lane >> 2, scb = lane & 3;
    auto stage = [&](int k0, int bufi) {
        ushort* Asb = SM + bufi * 4096;
        ushort* Bsb = SM + 12288 + bufi * 2048;
#pragma unroll
        for (int i2 = 0; i2 < 2; ++i2) {
            const int i = wave * 2 + i2;
            gld_lds16(aob + (size_t)(m0 + i * 16 + slr) * 1024 + k0 + scb * 8,
                      Asb + i * 512);
        }
        gld_lds16(wob + (size_t)(n0 + wave * 16 + slr) * 1024 + k0 + scb * 8,
                  Bsb + wave * 512);
    };

    f32x4 acc[2][4] = {};
    stage(0, 0);
    stage(32, 1);

    for (int kt = 0; kt < 32; ++kt) {
        const int cur = kt % 3;
        WAIT_BARRIER(3);
        stage(((kt + 2) & 31) * 32, (kt + 2) % 3);
        const ushort* Asb = SM + cur * 4096;
        const ushort* Bsb = SM + 12288 + cur * 2048;
        bf16x8 af[2], bfr[4];
#pragma unroll
        for (int i = 0; i < 2; ++i)
            af[i] = *(const bf16x8*)(Asb + (wave * 32 + i * 16 + lidx) * 32 + quad * 8);
#pragma unroll
        for (int i = 0; i < 4; ++i)
            bfr[i] = *(const bf16x8*)(Bsb + (i * 16 + lidx) * 32 + quad * 8);
#pragma unroll
        for (int mi = 0; mi < 2; ++mi)
#pragma unroll
            for (int ni = 0; ni < 4; ++ni)
                acc[mi][ni] = MFMA(af[mi], bfr[ni], acc[mi][ni]);
    }

#pragma unroll
    for (int mi = 0; mi < 2; ++mi)
#pragma unroll
        for (int ni = 0; ni < 4; ++ni)
#pragma unroll
            for (int r = 0; r < 4; ++r) {
                const int m = m0 + wave * 32 + mi * 16 + quad * 4 + r;
                const int n = n0 + ni * 16 + lidx;
                outf[(size_t)m * 1024 + n] = acc[mi][ni][r] + bias[n];
            }
}

// ---------------- flash_attn v7: 2-subtile waves at 2 blocks/CU --------------
// 256 thr, 4 waves x 32 Q-rows = 128 rows/block; grid (16,32) = 512 blocks.
// Double-buffer + __syncthreads (v2-v5 known-correct structure; prefetch has a
// full iteration of slack so the barrier's vmcnt(0) drain is free here).
__global__ __launch_bounds__(256) void flash_attn(
    const ushort* __restrict__ Qh, const ushort* __restrict__ Kh,
    const ushort* __restrict__ Vt, ushort* __restrict__ AO)
{
    __shared__ __align__(16) ushort Kb[2][4096];
    __shared__ __align__(16) ushort Vb[2][4096];
    __shared__ __align__(16) ushort P[4][16][LDP];  // wave-private, subtile reuse

    const int tid  = threadIdx.x;
    const int wave = tid >> 6, lane = tid & 63;
    const int quad = lane >> 4, lidx = lane & 15;
    const int bh = blockIdx.y;
    const int b = bh >> 4, h = bh & 15;
    const int qbase = blockIdx.x * 128 + wave * 32;

    const ushort* Qp = Qh + (size_t)bh * 2048 * 64;
    const ushort* Kp = Kh + (size_t)bh * 2048 * 64;
    const ushort* Vp = Vt + (size_t)bh * 64 * 2048;

    // Q fragments (2 subtiles x 16 rows), prescaled by (1/8)*log2(e)
    bf16x8 q[2][2];
#pragma unroll
    for (int t = 0; t < 2; ++t) {
        const ushort* qr = Qp + (size_t)(qbase + t * 16 + lidx) * 64 + quad * 8;
        union { ushort u[8]; uint4 v; } t0, t1;
        t0.v = *(const uint4*)qr;
        t1.v = *(const uint4*)(qr + 32);
#pragma unroll
        for (int i = 0; i < 8; ++i) {
            ((short*)&q[t][0])[i] = (short)f2bf(bf2f(t0.u[i]) * 0.18033688f);
            ((short*)&q[t][1])[i] = (short)f2bf(bf2f(t1.u[i]) * 0.18033688f);
        }
    }

    // staging: wave w stages chunks {2w, 2w+1}: 2 K-gld + 2 V-gld
    auto stage = [&](int s0, int bufi) {
#pragma unroll
        for (int i = 0; i < 2; ++i) {
            const int c = wave * 2 + i;
            const int slot = c * 64 + lane;
            const int r  = slot >> 3;
            const int bb = slot & 7;
            const int gb = bb ^ (r & 7);
            gld_lds16(Kp + (size_t)(s0 + r) * 64 + gb * 8, &Kb[bufi][c * 512]);
            gld_lds16(Vp + (size_t)r * 2048 + s0 + gb * 8, &Vb[bufi][c * 512]);
        }
    };

    float lsum[2][4] = {};
    f32x4 o[2][4] = {};

    stage(0, 0);
    __syncthreads();

    for (int j = 0; j < 32; ++j) {
        const int cur = j & 1;
        stage(((j + 1) & 31) * 64, cur ^ 1);

        // QK^T: K frags shared across both subtiles
        f32x4 s[2][4] = {};
#pragma unroll
        for (int n0 = 0; n0 < 4; ++n0) {
            const int row = n0 * 16 + lidx;
            bf16x8 k0 = *(const bf16x8*)&Kb[cur][row * 64 + ((quad ^ (row & 7)) * 8)];
            bf16x8 k1 = *(const bf16x8*)&Kb[cur][row * 64 + (((4 + quad) ^ (row & 7)) * 8)];
#pragma unroll
            for (int t = 0; t < 2; ++t) {
                s[t][n0] = MFMA(q[t][0], k0, s[t][n0]);
                s[t][n0] = MFMA(q[t][1], k1, s[t][n0]);
            }
        }

        // unnormalized softmax, P round-trip per subtile (DS in-order per wave)
        bf16x8 pf[2][2];
#pragma unroll
        for (int t = 0; t < 2; ++t) {
#pragma unroll
            for (int n0 = 0; n0 < 4; ++n0)
#pragma unroll
                for (int r = 0; r < 4; r += 2) {
                    const float pa = __builtin_amdgcn_exp2f(s[t][n0][r]);
                    const float pb = __builtin_amdgcn_exp2f(s[t][n0][r + 1]);
                    lsum[t][r] += pa;
                    lsum[t][r + 1] += pb;
                    const ushort2 u2 = pk2bf(pa, pb);
                    P[wave][quad * 4 + r][n0 * 16 + lidx] = u2.x;
                    P[wave][quad * 4 + r + 1][n0 * 16 + lidx] = u2.y;
                }
            asm volatile("s_waitcnt lgkmcnt(0)" ::: "memory");
            pf[t][0] = *(const bf16x8*)&P[wave][lidx][quad * 8];
            pf[t][1] = *(const bf16x8*)&P[wave][lidx][32 + quad * 8];
        }

        // P @ V: V frags shared across both subtiles
#pragma unroll
        for (int n0 = 0; n0 < 4; ++n0) {
            const int d = n0 * 16 + lidx;
            bf16x8 v0 = *(const bf16x8*)&Vb[cur][d * 64 + ((quad ^ (d & 7)) * 8)];
            bf16x8 v1 = *(const bf16x8*)&Vb[cur][d * 64 + (((4 + quad) ^ (d & 7)) * 8)];
#pragma unroll
            for (int t = 0; t < 2; ++t) {
                o[t][n0] = MFMA(pf[t][0], v0, o[t][n0]);
                o[t][n0] = MFMA(pf[t][1], v1, o[t][n0]);
            }
        }
        __syncthreads();
    }

#pragma unroll
    for (int t = 0; t < 2; ++t)
#pragma unroll
        for (int r = 0; r < 4; ++r) {
            float v = lsum[t][r];
            v += __shfl_xor(v, 1);
            v += __shfl_xor(v, 2);
            v += __shfl_xor(v, 4);
            v += __shfl_xor(v, 8);
            lsum[t][r] = v;
        }

#pragma unroll
    for (int t = 0; t < 2; ++t)
#pragma unroll
        for (int n0 = 0; n0 < 4; ++n0)
#pragma unroll
            for (int r = 0; r < 4; r += 2) {
                const int tt = qbase + t * 16 + quad * 4 + r;
                const int d  = n0 * 16 + lidx;
                const ushort2 u2 = pk2bf(o[t][n0][r] / lsum[t][r],
                                         o[t][n0][r + 1] / lsum[t][r + 1]);
                AO[(size_t)(b * 2048 + tt) * 1024 + h * 64 + d] = u2.x;
                AO[(size_t)(b * 2048 + tt + 1) * 1024 + h * 64 + d] = u2.y;
            }
}

extern "C" void kernel_launch(void* const* d_in, const int* in_sizes, int n_in,
                              void* d_out, int out_size, void* d_ws, size_t ws_size,
                              hipStream_t stream) {
    const float* xt = (const float*)d_in[0];
    const float* xs = (const float*)d_in[1];
    const float* Wq = (const float*)d_in[2];
    const float* Wk = (const float*)d_in[3];
    const float* Wv = (const float*)d_in[4];
    const float* Wo = (const float*)d_in[5];
    const float* bo = (const float*)d_in[6];
    float* out = (float*)d_out;

    ushort* ws = (ushort*)d_ws;

    cast_bf16<<<dim3(1024, 6, 1), 256, 0, stream>>>(xt, xs, Wq, Wk, Wv, Wo, ws);

    gemm128<<<dim3(8, 32, 3), 256, 0, stream>>>(
        ws + WS_XT, ws + WS_XS, ws + WS_WQ, ws + WS_WK, ws + WS_WV,
        ws + WS_QH, ws + WS_KH, ws + WS_VT);

    flash_attn<<<dim3(16, 32, 1), 256, 0, stream>>>(
        ws + WS_QH, ws + WS_KH, ws + WS_VT, ws + WS_AO);

    gemm_out<<<dim3(16, 32, 1), 256, 0, stream>>>(
        ws + WS_AO, ws + WS_WO, bo, out);
}

// Round 11
// 206.359 us; speedup vs baseline: 1.0700x; 1.0240x over previous
//
#include <hip/hip_runtime.h>
#include <hip/hip_bf16.h>

typedef short bf16x8 __attribute__((ext_vector_type(8)));
typedef float f32x4 __attribute__((ext_vector_type(4)));

#define LDP 72  // flash P row stride

__device__ __forceinline__ float bf2f(ushort u) {
    union { unsigned int i; float f; } v; v.i = ((unsigned int)u) << 16; return v.f;
}
__device__ __forceinline__ ushort f2bf(float f) {
    union { float f; unsigned int i; } v; v.f = f;
    unsigned int x = v.i;
    x += 0x7fffu + ((x >> 16) & 1u);  // RNE (finite values only)
    return (ushort)(x >> 16);
}

#define MFMA(a, b, c) __builtin_amdgcn_mfma_f32_16x16x32_bf16(a, b, c, 0, 0, 0)

// fine-grained barrier: wait for all but the newest N vmem ops, then s_barrier.
#define WAIT_BARRIER(N) asm volatile("s_waitcnt vmcnt(" #N ")\n\ts_barrier" ::: "memory")

// async global->LDS, 16B/lane; LDS dest = wave-uniform base + lane*16
__device__ __forceinline__ void gld_lds16(const ushort* g, ushort* l) {
    __builtin_amdgcn_global_load_lds(
        (const __attribute__((address_space(1))) unsigned int*)g,
        (__attribute__((address_space(3))) unsigned int*)l, 16, 0, 0);
}

// ws layout (ushort elems)
#define WS_XT 0
#define WS_XS 4194304
#define WS_WQ 8388608
#define WS_WK 9437184
#define WS_WV 10485760
#define WS_WO 11534336
#define WS_QH 12582912
#define WS_KH 16777216
#define WS_VT 20971520
#define WS_AO 0   // reuses XT region (XT dead after qkv_gemm)

// ---------------- cast: fp32 -> bf16 into ws ----------------
__global__ __launch_bounds__(256) void cast_bf16(
    const float* __restrict__ s0, const float* __restrict__ s1,
    const float* __restrict__ s2, const float* __restrict__ s3,
    const float* __restrict__ s4, const float* __restrict__ s5,
    ushort* __restrict__ ws)
{
    const int seg = blockIdx.y;
    const float* src = seg == 0 ? s0 : seg == 1 ? s1 : seg == 2 ? s2
                     : seg == 3 ? s3 : seg == 4 ? s4 : s5;
    const size_t off = seg == 0 ? WS_XT : seg == 1 ? WS_XS : seg == 2 ? WS_WQ
                     : seg == 3 ? WS_WK : seg == 4 ? WS_WV : (size_t)WS_WO;
    const int n4 = (seg < 2) ? 1048576 : 262144;  // float4 count
    ushort* d = ws + off;
    for (int i = blockIdx.x * 256 + threadIdx.x; i < n4; i += gridDim.x * 256) {
        float4 f = ((const float4*)src)[i];
        ushort4 u;
        u.x = f2bf(f.x); u.y = f2bf(f.y); u.z = f2bf(f.z); u.w = f2bf(f.w);
        ((ushort4*)d)[i] = u;
    }
}

// ---------------- qkv GEMM: 128x128 tile, tri-buffer fine-vmcnt --------------
// grid (8, 32, 3): z = 0:Q, 1:K, 2:Vt. All epilogues now route through LDS
// for 16B coalesced stores (Q/K previously: 64 scattered 2B stores/thread).
__global__ __launch_bounds__(256) void gemm128(
    const ushort* __restrict__ xtb, const ushort* __restrict__ xsb,
    const ushort* __restrict__ wqb, const ushort* __restrict__ wkb,
    const ushort* __restrict__ wvb,
    ushort* __restrict__ qh, ushort* __restrict__ kh, ushort* __restrict__ vt)
{
    __shared__ __align__(16) ushort SM[24576];  // A: 3x4096, B: 12288 + 3x4096

    const int mode = blockIdx.z;
    const ushort* Ap = (mode == 0) ? xtb : xsb;
    const ushort* Wp = (mode == 0) ? wqb : (mode == 1 ? wkb : wvb);

    const int tid  = threadIdx.x;
    const int wave = tid >> 6, lane = tid & 63;
    const int quad = lane >> 4, lidx = lane & 15;
    const int wm = wave >> 1, wn = wave & 1;
    const int m0 = blockIdx.y * 128, n0 = blockIdx.x * 128;

    const int slr = lane >> 2, scb = lane & 3;
    auto stage = [&](int k0, int bufi) {
        ushort* Asb = SM + bufi * 4096;
        ushort* Bsb = SM + 12288 + bufi * 4096;
#pragma unroll
        for (int i2 = 0; i2 < 2; ++i2) {
            const int i = wave + i2 * 4;
            const int r = i * 16 + slr;
            gld_lds16(Ap + (size_t)(m0 + r) * 1024 + k0 + scb * 8, Asb + i * 512);
            gld_lds16(Wp + (size_t)(n0 + r) * 1024 + k0 + scb * 8, Bsb + i * 512);
        }
    };

    f32x4 acc[4][4] = {};
    stage(0, 0);
    stage(32, 1);

    for (int kt = 0; kt < 32; ++kt) {
        const int cur = kt % 3;
        WAIT_BARRIER(4);
        stage(((kt + 2) & 31) * 32, (kt + 2) % 3);
        const ushort* Asb = SM + cur * 4096;
        const ushort* Bsb = SM + 12288 + cur * 4096;
        bf16x8 af[4], bfr[4];
#pragma unroll
        for (int i = 0; i < 4; ++i) {
            af[i]  = *(const bf16x8*)(Asb + (wm * 64 + i * 16 + lidx) * 32 + quad * 8);
            bfr[i] = *(const bf16x8*)(Bsb + (wn * 64 + i * 16 + lidx) * 32 + quad * 8);
        }
#pragma unroll
        for (int mi = 0; mi < 4; ++mi)
#pragma unroll
            for (int ni = 0; ni < 4; ++ni)
                acc[mi][ni] = MFMA(af[mi], bfr[ni], acc[mi][ni]);
    }
    __syncthreads();  // full drain once: epilogue reuses SM as scratch

    ushort* scr = SM + wave * 4096;  // wave-private 8 KB (64x64 tile)

    if (mode == 2) {
        // Vt: scr[dl][swz(tl)] then coalesced stores along t
#pragma unroll
        for (int mi = 0; mi < 4; ++mi)
#pragma unroll
            for (int ni = 0; ni < 4; ++ni)
#pragma unroll
                for (int r = 0; r < 4; ++r) {
                    const int dl = ni * 16 + lidx;
                    const int tl = mi * 16 + quad * 4 + r;
                    const int col = (((tl >> 3) ^ (dl & 7)) << 3) | (tl & 7);
                    scr[dl * 64 + col] = f2bf(acc[mi][ni][r]);
                }
        asm volatile("s_waitcnt lgkmcnt(0)" ::: "memory");
        const int hh = (n0 + wn * 64) >> 6;
        const int bb = m0 >> 11;
        const int t0 = (m0 + wm * 64) & 2047;
        ushort* Vtp = vt + (size_t)(bb * 16 + hh) * 64 * 2048;
#pragma unroll
        for (int ii = 0; ii < 8; ++ii) {
            const int dl = ii * 8 + (lane >> 3);
            const int tb = lane & 7;
            uint4 vd = *(const uint4*)(scr + dl * 64 + ((tb ^ (dl & 7)) << 3));
            *(uint4*)(Vtp + (size_t)dl * 2048 + t0 + tb * 8) = vd;
        }
        return;
    }

    // Q/K: scr[tl][swz(dl)] then coalesced 16B stores along d (one head/wave)
#pragma unroll
    for (int mi = 0; mi < 4; ++mi)
#pragma unroll
        for (int ni = 0; ni < 4; ++ni)
#pragma unroll
            for (int r = 0; r < 4; ++r) {
                const int tl = mi * 16 + quad * 4 + r;
                const int dl = ni * 16 + lidx;
                const int col = (((dl >> 3) ^ (tl & 7)) << 3) | (dl & 7);
                scr[tl * 64 + col] = f2bf(acc[mi][ni][r]);
            }
    asm volatile("s_waitcnt lgkmcnt(0)" ::: "memory");
    {
        ushort* dst = (mode == 0) ? qh : kh;
        const int hh = (n0 + wn * 64) >> 6;
        const int bb = m0 >> 11;
        const int tbase = (m0 + wm * 64) & 2047;
        ushort* Hp = dst + (size_t)(bb * 16 + hh) * 2048 * 64;
#pragma unroll
        for (int ii = 0; ii < 8; ++ii) {
            const int tl = ii * 8 + (lane >> 3);
            const int c  = lane & 7;
            uint4 vd = *(const uint4*)(scr + tl * 64 + ((c ^ (tl & 7)) << 3));
            *(uint4*)(Hp + (size_t)(tbase + tl) * 64 + c * 8) = vd;
        }
    }
}

// ---------------- out GEMM: 128x64 tile, tri-buffer fine-vmcnt ---------------
__global__ __launch_bounds__(256) void gemm_out(
    const ushort* __restrict__ aob, const ushort* __restrict__ wob,
    const float* __restrict__ bias, float* __restrict__ outf)
{
    __shared__ __align__(16) ushort SM[18432];

    const int tid  = threadIdx.x;
    const int wave = tid >> 6, lane = tid & 63;
    const int quad = lane >> 4, lidx = lane & 15;
    const int m0 = blockIdx.y * 128, n0 = blockIdx.x * 64;

    const int slr = lane >> 2, scb = lane & 3;
    auto stage = [&](int k0, int bufi) {
        ushort* Asb = SM + bufi * 4096;
        ushort* Bsb = SM + 12288 + bufi * 2048;
#pragma unroll
        for (int i2 = 0; i2 < 2; ++i2) {
            const int i = wave * 2 + i2;
            gld_lds16(aob + (size_t)(m0 + i * 16 + slr) * 1024 + k0 + scb * 8,
                      Asb + i * 512);
        }
        gld_lds16(wob + (size_t)(n0 + wave * 16 + slr) * 1024 + k0 + scb * 8,
                  Bsb + wave * 512);
    };

    f32x4 acc[2][4] = {};
    stage(0, 0);
    stage(32, 1);

    for (int kt = 0; kt < 32; ++kt) {
        const int cur = kt % 3;
        WAIT_BARRIER(3);
        stage(((kt + 2) & 31) * 32, (kt + 2) % 3);
        const ushort* Asb = SM + cur * 4096;
        const ushort* Bsb = SM + 12288 + cur * 2048;
        bf16x8 af[2], bfr[4];
#pragma unroll
        for (int i = 0; i < 2; ++i)
            af[i] = *(const bf16x8*)(Asb + (wave * 32 + i * 16 + lidx) * 32 + quad * 8);
#pragma unroll
        for (int i = 0; i < 4; ++i)
            bfr[i] = *(const bf16x8*)(Bsb + (i * 16 + lidx) * 32 + quad * 8);
#pragma unroll
        for (int mi = 0; mi < 2; ++mi)
#pragma unroll
            for (int ni = 0; ni < 4; ++ni)
                acc[mi][ni] = MFMA(af[mi], bfr[ni], acc[mi][ni]);
    }

#pragma unroll
    for (int mi = 0; mi < 2; ++mi)
#pragma unroll
        for (int ni = 0; ni < 4; ++ni)
#pragma unroll
            for (int r = 0; r < 4; ++r) {
                const int m = m0 + wave * 32 + mi * 16 + quad * 4 + r;
                const int n = n0 + ni * 16 + lidx;
                outf[(size_t)m * 1024 + n] = acc[mi][ni][r] + bias[n];
            }
}

// ---------------- flash_attn v4 (exact R7 restore; measured 63.3 us) ---------
// grid (16, 32), 512 thr; wave handles 16 Q rows; at the LDS-pipe roof.
__global__ __launch_bounds__(512) void flash_attn(
    const ushort* __restrict__ Qh, const ushort* __restrict__ Kh,
    const ushort* __restrict__ Vt, ushort* __restrict__ AO)
{
    __shared__ __align__(16) ushort Kb[2][4096];
    __shared__ __align__(16) ushort Vb[2][4096];
    __shared__ __align__(16) ushort P[8][16][LDP];

    const int tid  = threadIdx.x;
    const int wave = tid >> 6, lane = tid & 63;
    const int quad = lane >> 4, lidx = lane & 15;
    const int bh = blockIdx.y;
    const int b = bh >> 4, h = bh & 15;
    const int qbase = blockIdx.x * 128 + wave * 16;

    const ushort* Qp = Qh + (size_t)bh * 2048 * 64;
    const ushort* Kp = Kh + (size_t)bh * 2048 * 64;
    const ushort* Vp = Vt + (size_t)bh * 64 * 2048;

    bf16x8 q0, q1;
    {
        const ushort* qr = Qp + (size_t)(qbase + lidx) * 64 + quad * 8;
        union { ushort u[8]; uint4 v; } t0, t1;
        t0.v = *(const uint4*)qr;
        t1.v = *(const uint4*)(qr + 32);
#pragma unroll
        for (int i = 0; i < 8; ++i) {
            ((short*)&q0)[i] = (short)f2bf(bf2f(t0.u[i]) * 0.18033688f);
            ((short*)&q1)[i] = (short)f2bf(bf2f(t1.u[i]) * 0.18033688f);
        }
    }

    auto stage = [&](int s0, int bufi) {
        const int slot = wave * 64 + lane;
        const int r  = slot >> 3;
        const int bb = slot & 7;
        const int gb = bb ^ (r & 7);
        gld_lds16(Kp + (size_t)(s0 + r) * 64 + gb * 8, &Kb[bufi][wave * 512]);
        gld_lds16(Vp + (size_t)r * 2048 + s0 + gb * 8, &Vb[bufi][wave * 512]);
    };

    float lsum[4] = {};
    f32x4 o[4] = {};

    stage(0, 0);
    __syncthreads();

    for (int j = 0; j < 32; ++j) {
        const int cur = j & 1;
        stage(((j + 1) & 31) * 64, cur ^ 1);

        f32x4 s[4] = {};
#pragma unroll
        for (int n0 = 0; n0 < 4; ++n0) {
            const int row = n0 * 16 + lidx;
            bf16x8 k0 = *(const bf16x8*)&Kb[cur][row * 64 + ((quad ^ (row & 7)) * 8)];
            bf16x8 k1 = *(const bf16x8*)&Kb[cur][row * 64 + (((4 + quad) ^ (row & 7)) * 8)];
            s[n0] = MFMA(q0, k0, s[n0]);
            s[n0] = MFMA(q1, k1, s[n0]);
        }

#pragma unroll
        for (int n0 = 0; n0 < 4; ++n0)
#pragma unroll
            for (int r = 0; r < 4; ++r) {
                const float p = __builtin_amdgcn_exp2f(s[n0][r]);
                lsum[r] += p;
                P[wave][quad * 4 + r][n0 * 16 + lidx] = f2bf(p);
            }
        asm volatile("s_waitcnt lgkmcnt(0)" ::: "memory");
        bf16x8 p0 = *(const bf16x8*)&P[wave][lidx][quad * 8];
        bf16x8 p1 = *(const bf16x8*)&P[wave][lidx][32 + quad * 8];

#pragma unroll
        for (int n0 = 0; n0 < 4; ++n0) {
            const int d = n0 * 16 + lidx;
            bf16x8 v0 = *(const bf16x8*)&Vb[cur][d * 64 + ((quad ^ (d & 7)) * 8)];
            bf16x8 v1 = *(const bf16x8*)&Vb[cur][d * 64 + (((4 + quad) ^ (d & 7)) * 8)];
            o[n0] = MFMA(p0, v0, o[n0]);
            o[n0] = MFMA(p1, v1, o[n0]);
        }
        __syncthreads();
    }

#pragma unroll
    for (int r = 0; r < 4; ++r) {
        float v = lsum[r];
        v += __shfl_xor(v, 1);
        v += __shfl_xor(v, 2);
        v += __shfl_xor(v, 4);
        v += __shfl_xor(v, 8);
        lsum[r] = v;
    }

#pragma unroll
    for (int n0 = 0; n0 < 4; ++n0)
#pragma unroll
        for (int r = 0; r < 4; ++r) {
            const int tt = qbase + quad * 4 + r;
            const int d  = n0 * 16 + lidx;
            AO[(size_t)(b * 2048 + tt) * 1024 + h * 64 + d] =
                f2bf(o[n0][r] / lsum[r]);
        }
}

extern "C" void kernel_launch(void* const* d_in, const int* in_sizes, int n_in,
                              void* d_out, int out_size, void* d_ws, size_t ws_size,
                              hipStream_t stream) {
    const float* xt = (const float*)d_in[0];
    const float* xs = (const float*)d_in[1];
    const float* Wq = (const float*)d_in[2];
    const float* Wk = (const float*)d_in[3];
    const float* Wv = (const float*)d_in[4];
    const float* Wo = (const float*)d_in[5];
    const float* bo = (const float*)d_in[6];
    float* out = (float*)d_out;

    ushort* ws = (ushort*)d_ws;

    cast_bf16<<<dim3(1024, 6, 1), 256, 0, stream>>>(xt, xs, Wq, Wk, Wv, Wo, ws);

    gemm128<<<dim3(8, 32, 3), 256, 0, stream>>>(
        ws + WS_XT, ws + WS_XS, ws + WS_WQ, ws + WS_WK, ws + WS_WV,
        ws + WS_QH, ws + WS_KH, ws + WS_VT);

    flash_attn<<<dim3(16, 32, 1), 512, 0, stream>>>(
        ws + WS_QH, ws + WS_KH, ws + WS_VT, ws + WS_AO);

    gemm_out<<<dim3(16, 32, 1), 256, 0, stream>>>(
        ws + WS_AO, ws + WS_WO, bo, out);
}